// Round 2
// baseline (12096.278 us; speedup 1.0000x reference)
//
#include <hip/hip_runtime.h>
#include <math.h>

#define BB   64
#define TENC 128
#define TDEC 64
#define DHH  1024
#define DVV  2048
#define NCHN 256
#define GG   8704   // 4*DV + 2*NCH
#define KTOT 3072   // DH + DV

typedef unsigned short u16;
typedef __bf16 bf16x8 __attribute__((ext_vector_type(8)));
typedef float  f32x4  __attribute__((ext_vector_type(4)));

__device__ __forceinline__ float sigmoidf_(float x) { return 1.f / (1.f + expf(-x)); }
__device__ __forceinline__ u16 f2bf(float f) {
    unsigned u = __float_as_uint(f);
    unsigned r = (u + 0x7fffu + ((u >> 16) & 1u)) >> 16;
    return (u16)r;
}
__device__ __forceinline__ float bf2f(u16 s) { return __uint_as_float(((unsigned)s) << 16); }

// ===================== shared kernels (both paths) =====================

// -------- P = enc(8192x1024) @ W1(1024x1024) + b1 (f32, runs once) --------
__global__ __launch_bounds__(256) void k_P(const float* __restrict__ enc,
                                           const float* __restrict__ W1,
                                           const float* __restrict__ b1,
                                           float* __restrict__ P) {
    __shared__ float As[32][68];
    __shared__ float Bs[32][68];
    int j0 = blockIdx.x * 64;
    int m0 = blockIdx.y * 64;
    int tid = threadIdx.x;
    int jg = tid & 15, bg = tid >> 4;
    float acc[4][4] = {};
    for (int k0 = 0; k0 < DHH; k0 += 32) {
#pragma unroll
        for (int p = 0; p < 8; ++p) {
            int r = p * 8 + (tid >> 5);
            int kk = tid & 31;
            As[kk][r] = enc[(size_t)(m0 + r) * DHH + k0 + kk];
        }
#pragma unroll
        for (int p = 0; p < 8; ++p) {
            int kk = p * 4 + (tid >> 6);
            int jl = tid & 63;
            Bs[kk][jl] = W1[(size_t)(k0 + kk) * DHH + j0 + jl];
        }
        __syncthreads();
#pragma unroll
        for (int kk = 0; kk < 32; ++kk) {
            float4 a = *(const float4*)&As[kk][bg * 4];
            float4 b = *(const float4*)&Bs[kk][jg * 4];
            float av[4] = {a.x, a.y, a.z, a.w};
            float bv[4] = {b.x, b.y, b.z, b.w};
#pragma unroll
            for (int i = 0; i < 4; ++i)
#pragma unroll
                for (int j = 0; j < 4; ++j) acc[i][j] += av[i] * bv[j];
        }
        __syncthreads();
    }
    float4 bb = *(const float4*)&b1[j0 + jg * 4];
    float bia[4] = {bb.x, bb.y, bb.z, bb.w};
#pragma unroll
    for (int i = 0; i < 4; ++i) {
        int r = m0 + bg * 4 + i;
        float4 v = make_float4(acc[i][0] + bia[0], acc[i][1] + bia[1],
                               acc[i][2] + bia[2], acc[i][3] + bia[3]);
        *(float4*)&P[(size_t)r * DHH + j0 + jg * 4] = v;
    }
}

// -------- e[b,t] = sum_d tanh(P[b,t,d] + hW[b,d]) * w2[d] (reduces 8 hW partials)
__global__ __launch_bounds__(256) void k_e(const float* __restrict__ P,
                                           const float* __restrict__ hWp,
                                           const float* __restrict__ w2,
                                           float* __restrict__ e) {
    int b = blockIdx.x, tg = blockIdx.y;
    __shared__ float hw[DHH];
    __shared__ float w2s[DHH];
    int tid = threadIdx.x;
#pragma unroll
    for (int p = 0; p < 4; ++p) {
        int d = p * 256 + tid;
        float s = 0.f;
#pragma unroll
        for (int ks = 0; ks < 8; ++ks) s += hWp[(ks * 64 + b) * DHH + d];
        hw[d] = s;
        w2s[d] = w2[d];
    }
    __syncthreads();
    int wave = tid >> 6, lane = tid & 63;
    const float* Pb = P + (size_t)b * TENC * DHH;
    for (int tt = 0; tt < 8; ++tt) {
        int t = tg * 32 + wave * 8 + tt;
        const float* Pr = Pb + (size_t)t * DHH;
        float s = 0.f;
#pragma unroll
        for (int i = 0; i < 16; ++i) {
            int d = i * 64 + lane;
            s += tanhf(Pr[d] + hw[d]) * w2s[d];
        }
#pragma unroll
        for (int off = 32; off > 0; off >>= 1) s += __shfl_down(s, off);
        if (lane == 0) e[b * TENC + t] = s;
    }
}

// ===================== NEW MFMA path =====================

// zero recurrent state + bf16 x buffers
__global__ __launch_bounds__(256) void k_init2(float* __restrict__ c,
                                               u16* __restrict__ xh,
                                               u16* __restrict__ xl) {
    int i = blockIdx.x * 256 + threadIdx.x;   // grid 768 -> 196608
    xh[i] = 0; xl[i] = 0;
    if (i < BB * DVV) c[i] = 0.f;
}

// transpose+convert: D[n][k] = bf16(S[k][n]) (hi, and optionally lo residual)
template <bool LO>
__global__ __launch_bounds__(256) void k_cvt(const float* __restrict__ S1,
                                             const float* __restrict__ S2,
                                             int K1, int N, int K,
                                             u16* __restrict__ Dh,
                                             u16* __restrict__ Dl) {
    __shared__ float t[64][65];
    int n0 = blockIdx.x * 64, k0 = blockIdx.y * 64;
    int tid = threadIdx.x;
    int cn = tid & 63, r4 = tid >> 6;
#pragma unroll
    for (int p = 0; p < 16; ++p) {
        int kk = p * 4 + r4;
        int kg = k0 + kk;
        const float* src = (kg < K1) ? S1 + (size_t)kg * N : S2 + (size_t)(kg - K1) * N;
        t[kk][cn] = src[n0 + cn];
    }
    __syncthreads();
    int ck = tid & 63, n4 = tid >> 6;
#pragma unroll
    for (int p = 0; p < 16; ++p) {
        int nn = p * 4 + n4;
        float w = t[ck][nn];
        u16 hi = f2bf(w);
        size_t o = (size_t)(n0 + nn) * K + k0 + ck;
        Dh[o] = hi;
        if (LO) Dl[o] = f2bf(w - bf2f(hi));
    }
}

// hW = x_h @ Wta^T : M=64, N=1024, K=2048, single bf16 term, ksplit 8
__global__ __launch_bounds__(256) void k_mma1(const u16* __restrict__ xh,
                                              const u16* __restrict__ Wta,
                                              float* __restrict__ hWp) {
    int n0 = blockIdx.x * 64;
    int kseg = blockIdx.y;                 // 8 segs of 256
    int wv = threadIdx.x >> 6, l = threadIdx.x & 63;
    int lr = l & 15, lk = (l >> 4) * 8;
    int n = n0 + wv * 16 + lr;
    const u16* wp = Wta + (size_t)n * 2048 + lk;
    const u16* ap = xh + (size_t)lr * KTOT + 1024 + lk;   // h part of x
    f32x4 z = {0.f, 0.f, 0.f, 0.f};
    f32x4 acc[4];
#pragma unroll
    for (int mf = 0; mf < 4; ++mf) acc[mf] = z;
    int kend = kseg * 256 + 256;
    for (int k = kseg * 256; k < kend; k += 32) {
        bf16x8 bfrag = *(const bf16x8*)(wp + k);
#pragma unroll
        for (int mf = 0; mf < 4; ++mf) {
            bf16x8 a = *(const bf16x8*)(ap + (size_t)mf * 16 * KTOT + k);
            acc[mf] = __builtin_amdgcn_mfma_f32_16x16x32_bf16(a, bfrag, acc[mf], 0, 0, 0);
        }
    }
    float* dst = hWp + (size_t)kseg * 64 * DHH;
#pragma unroll
    for (int mf = 0; mf < 4; ++mf)
#pragma unroll
        for (int r = 0; r < 4; ++r) {
            int m = mf * 16 + (l >> 4) * 4 + r;
            dst[(size_t)m * DHH + n] = acc[mf][r];
        }
}

// gates = x @ W^T, 3-term hi/lo split: xh*wh + xh*wl + xl*wh. M=64,N=8704,K=3072, ksplit 2
__global__ __launch_bounds__(256) void k_mma3(const u16* __restrict__ xh,
                                              const u16* __restrict__ xl,
                                              const u16* __restrict__ Wh,
                                              const u16* __restrict__ Wl,
                                              float* __restrict__ part) {
    int n0 = blockIdx.x * 64;
    int kseg = blockIdx.y;                 // 2 segs of 1536
    int wv = threadIdx.x >> 6, l = threadIdx.x & 63;
    int lr = l & 15, lk = (l >> 4) * 8;
    int n = n0 + wv * 16 + lr;
    const u16* wph = Wh + (size_t)n * KTOT + lk;
    const u16* wpl = Wl + (size_t)n * KTOT + lk;
    const u16* aph = xh + (size_t)lr * KTOT + lk;
    const u16* apl = xl + (size_t)lr * KTOT + lk;
    f32x4 z = {0.f, 0.f, 0.f, 0.f};
    f32x4 acc[4];
#pragma unroll
    for (int mf = 0; mf < 4; ++mf) acc[mf] = z;
    int kend = kseg * 1536 + 1536;
    for (int k = kseg * 1536; k < kend; k += 32) {
        bf16x8 bh = *(const bf16x8*)(wph + k);
        bf16x8 bl = *(const bf16x8*)(wpl + k);
#pragma unroll
        for (int mf = 0; mf < 4; ++mf) {
            size_t ao = (size_t)mf * 16 * KTOT + k;
            bf16x8 ah = *(const bf16x8*)(aph + ao);
            bf16x8 al = *(const bf16x8*)(apl + ao);
            acc[mf] = __builtin_amdgcn_mfma_f32_16x16x32_bf16(ah, bh, acc[mf], 0, 0, 0);
            acc[mf] = __builtin_amdgcn_mfma_f32_16x16x32_bf16(ah, bl, acc[mf], 0, 0, 0);
            acc[mf] = __builtin_amdgcn_mfma_f32_16x16x32_bf16(al, bh, acc[mf], 0, 0, 0);
        }
    }
    float* dst = part + (size_t)kseg * 64 * GG;
#pragma unroll
    for (int mf = 0; mf < 4; ++mf)
#pragma unroll
        for (int r = 0; r < 4; ++r) {
            int m = mf * 16 + (l >> 4) * 4 + r;
            dst[(size_t)m * GG + n] = acc[mf][r];
        }
}

// softmax over t + context -> bf16 hi/lo into x buffer (cols 0..1023)
__global__ __launch_bounds__(256) void k_sc2(const float* __restrict__ e,
                                             const float* __restrict__ enc,
                                             u16* __restrict__ xh,
                                             u16* __restrict__ xl) {
    int b = blockIdx.x, dg = blockIdx.y;
    __shared__ float al[TENC];
    __shared__ float red[256];
    int tid = threadIdx.x;
    float v = (tid < TENC) ? e[b * TENC + tid] : -3.0e38f;
    red[tid] = v;
    __syncthreads();
    for (int s = 128; s > 0; s >>= 1) {
        if (tid < s) red[tid] = fmaxf(red[tid], red[tid + s]);
        __syncthreads();
    }
    float mx = red[0];
    __syncthreads();
    float ex = (tid < TENC) ? expf(v - mx) : 0.f;
    red[tid] = ex;
    __syncthreads();
    for (int s = 128; s > 0; s >>= 1) {
        if (tid < s) red[tid] += red[tid + s];
        __syncthreads();
    }
    float inv = 1.f / red[0];
    if (tid < TENC) al[tid] = ex * inv;
    __syncthreads();
    int d = dg * 256 + tid;
    const float* ep = enc + (size_t)b * TENC * DHH + d;
    float acc = 0.f;
#pragma unroll 4
    for (int t = 0; t < TENC; ++t) acc += al[t] * ep[(size_t)t * DHH];
    u16 hi = f2bf(acc);
    xh[(size_t)b * KTOT + d] = hi;
    xl[(size_t)b * KTOT + d] = f2bf(acc - bf2f(hi));
}

// reduce 2 gate partials + biases, cumsoftmax, ON-LSTM update; h -> bf16 hi/lo + out
__global__ __launch_bounds__(256) void k_pw2(const float* __restrict__ part,
                                             const float* __restrict__ bih,
                                             const float* __restrict__ bhh,
                                             u16* __restrict__ xh,
                                             u16* __restrict__ xl,
                                             float* __restrict__ c,
                                             float* __restrict__ out, int t) {
    int b = blockIdx.x;
    __shared__ float g[GG];
    __shared__ float cs1[NCHN], cs2[NCHN], t1[NCHN], t2[NCHN];
    int tid = threadIdx.x;
    for (int p = 0; p < 34; ++p) {
        int j = p * 256 + tid;
        float s = bih[j] + bhh[j] + part[(size_t)b * GG + j] + part[(size_t)(64 + b) * GG + j];
        g[j] = s;
    }
    __syncthreads();
    float x1 = g[tid], x2 = g[NCHN + tid];
    t1[tid] = x1; t2[tid] = x2;
    __syncthreads();
    for (int s = 128; s > 0; s >>= 1) {
        if (tid < s) { t1[tid] = fmaxf(t1[tid], t1[tid + s]); t2[tid] = fmaxf(t2[tid], t2[tid + s]); }
        __syncthreads();
    }
    float m1 = t1[0], m2 = t2[0];
    __syncthreads();
    float e1 = expf(x1 - m1), e2 = expf(x2 - m2);
    t1[tid] = e1; t2[tid] = e2;
    __syncthreads();
    for (int s = 128; s > 0; s >>= 1) {
        if (tid < s) { t1[tid] += t1[tid + s]; t2[tid] += t2[tid + s]; }
        __syncthreads();
    }
    float inv1 = 1.f / t1[0], inv2 = 1.f / t2[0];
    __syncthreads();
    cs1[tid] = e1; cs2[tid] = e2;
    __syncthreads();
    for (int off = 1; off < NCHN; off <<= 1) {
        float a1 = (tid >= off) ? cs1[tid - off] : 0.f;
        float a2 = (tid >= off) ? cs2[tid - off] : 0.f;
        __syncthreads();
        cs1[tid] += a1; cs2[tid] += a2;
        __syncthreads();
    }
    float* cb = c + (size_t)b * DVV;
    float* ob = out + ((size_t)b * TDEC + t) * DVV;
    u16* xhb = xh + (size_t)b * KTOT + 1024;
    u16* xlb = xl + (size_t)b * KTOT + 1024;
    for (int p = 0; p < 8; ++p) {
        int idx = p * 256 + tid;
        int ch = idx >> 3;
        float cin = 1.f - cs1[ch] * inv1;
        float cfg = cs2[ch] * inv2;
        float ov = cfg * cin;
        float oo = sigmoidf_(g[512 + idx]);
        float gg = tanhf(g[2560 + idx]);
        float ii = sigmoidf_(g[4608 + idx]);
        float ff = sigmoidf_(g[6656 + idx]);
        float fg = ff * ov + (cfg - ov);
        float ig = ii * ov + (cin - ov);
        float cy = fg * cb[idx] + ig * gg;
        cb[idx] = cy;
        float hy = oo * tanhf(cy);
        ob[idx] = hy;
        u16 hh = f2bf(hy);
        xhb[idx] = hh;
        xlb[idx] = f2bf(hy - bf2f(hh));
    }
}

// ===================== OLD f32 fallback path =====================

__global__ __launch_bounds__(256) void k_init(float* __restrict__ h, float* __restrict__ c) {
    int i = blockIdx.x * 256 + threadIdx.x;
    h[i] = 0.f;
    c[i] = 0.f;
}

template <int KS>
__global__ __launch_bounds__(256) void k_skinny(const float* __restrict__ A1,
                                                const float* __restrict__ A2,
                                                const float* __restrict__ B1,
                                                const float* __restrict__ B2,
                                                int K1, int K2, int N,
                                                float* __restrict__ part) {
    __shared__ float As[32][68];
    __shared__ float Bs[32][68];
    int j0 = blockIdx.x * 64;
    int kseg = blockIdx.y;
    int tid = threadIdx.x;
    int jg = tid & 15, bg = tid >> 4;
    float acc[4][4] = {};
    for (int k0 = kseg * KS; k0 < (kseg + 1) * KS; k0 += 32) {
#pragma unroll
        for (int p = 0; p < 8; ++p) {
            int r = p * 8 + (tid >> 5);
            int kk = tid & 31;
            int k = k0 + kk;
            As[kk][r] = (k < K1) ? A1[r * K1 + k] : A2[r * K2 + (k - K1)];
        }
#pragma unroll
        for (int p = 0; p < 8; ++p) {
            int kk = p * 4 + (tid >> 6);
            int jl = tid & 63;
            int k = k0 + kk;
            Bs[kk][jl] = (k < K1) ? B1[(size_t)k * N + j0 + jl]
                                  : B2[(size_t)(k - K1) * N + j0 + jl];
        }
        __syncthreads();
#pragma unroll
        for (int kk = 0; kk < 32; ++kk) {
            float4 a = *(const float4*)&As[kk][bg * 4];
            float4 b = *(const float4*)&Bs[kk][jg * 4];
            float av[4] = {a.x, a.y, a.z, a.w};
            float bv[4] = {b.x, b.y, b.z, b.w};
#pragma unroll
            for (int i = 0; i < 4; ++i)
#pragma unroll
                for (int j = 0; j < 4; ++j) acc[i][j] += av[i] * bv[j];
        }
        __syncthreads();
    }
#pragma unroll
    for (int i = 0; i < 4; ++i) {
        int r = bg * 4 + i;
        float4 v = make_float4(acc[i][0], acc[i][1], acc[i][2], acc[i][3]);
        *(float4*)&part[(size_t)(kseg * 64 + r) * N + j0 + jg * 4] = v;
    }
}

__global__ __launch_bounds__(256) void k_sc_f32(const float* __restrict__ e,
                                                const float* __restrict__ enc,
                                                float* __restrict__ ctx) {
    int b = blockIdx.x, dg = blockIdx.y;
    __shared__ float al[TENC];
    __shared__ float red[256];
    int tid = threadIdx.x;
    float v = (tid < TENC) ? e[b * TENC + tid] : -3.0e38f;
    red[tid] = v;
    __syncthreads();
    for (int s = 128; s > 0; s >>= 1) {
        if (tid < s) red[tid] = fmaxf(red[tid], red[tid + s]);
        __syncthreads();
    }
    float mx = red[0];
    __syncthreads();
    float ex = (tid < TENC) ? expf(v - mx) : 0.f;
    red[tid] = ex;
    __syncthreads();
    for (int s = 128; s > 0; s >>= 1) {
        if (tid < s) red[tid] += red[tid + s];
        __syncthreads();
    }
    float inv = 1.f / red[0];
    if (tid < TENC) al[tid] = ex * inv;
    __syncthreads();
    int d = dg * 256 + tid;
    const float* ep = enc + (size_t)b * TENC * DHH + d;
    float acc = 0.f;
#pragma unroll 4
    for (int t = 0; t < TENC; ++t) acc += al[t] * ep[(size_t)t * DHH];
    ctx[b * DHH + d] = acc;
}

__global__ __launch_bounds__(256) void k_pw_f32(const float* __restrict__ part,
                                                const float* __restrict__ bih,
                                                const float* __restrict__ bhh,
                                                float* __restrict__ h,
                                                float* __restrict__ c,
                                                float* __restrict__ out, int t) {
    int b = blockIdx.x;
    __shared__ float g[GG];
    __shared__ float cs1[NCHN], cs2[NCHN], t1[NCHN], t2[NCHN];
    int tid = threadIdx.x;
    for (int p = 0; p < 34; ++p) {
        int j = p * 256 + tid;
        float s = bih[j] + bhh[j];
#pragma unroll
        for (int ks = 0; ks < 6; ++ks) s += part[(size_t)(ks * 64 + b) * GG + j];
        g[j] = s;
    }
    __syncthreads();
    float x1 = g[tid], x2 = g[NCHN + tid];
    t1[tid] = x1; t2[tid] = x2;
    __syncthreads();
    for (int s = 128; s > 0; s >>= 1) {
        if (tid < s) { t1[tid] = fmaxf(t1[tid], t1[tid + s]); t2[tid] = fmaxf(t2[tid], t2[tid + s]); }
        __syncthreads();
    }
    float m1 = t1[0], m2 = t2[0];
    __syncthreads();
    float e1 = expf(x1 - m1), e2 = expf(x2 - m2);
    t1[tid] = e1; t2[tid] = e2;
    __syncthreads();
    for (int s = 128; s > 0; s >>= 1) {
        if (tid < s) { t1[tid] += t1[tid + s]; t2[tid] += t2[tid + s]; }
        __syncthreads();
    }
    float inv1 = 1.f / t1[0], inv2 = 1.f / t2[0];
    __syncthreads();
    cs1[tid] = e1; cs2[tid] = e2;
    __syncthreads();
    for (int off = 1; off < NCHN; off <<= 1) {
        float a1 = (tid >= off) ? cs1[tid - off] : 0.f;
        float a2 = (tid >= off) ? cs2[tid - off] : 0.f;
        __syncthreads();
        cs1[tid] += a1; cs2[tid] += a2;
        __syncthreads();
    }
    float* cb = c + (size_t)b * DVV;
    float* hb = h + (size_t)b * DVV;
    float* ob = out + ((size_t)b * TDEC + t) * DVV;
    for (int p = 0; p < 8; ++p) {
        int idx = p * 256 + tid;
        int ch = idx >> 3;
        float cin = 1.f - cs1[ch] * inv1;
        float cfg = cs2[ch] * inv2;
        float ov = cfg * cin;
        float oo = sigmoidf_(g[512 + idx]);
        float gg = tanhf(g[2560 + idx]);
        float ii = sigmoidf_(g[4608 + idx]);
        float ff = sigmoidf_(g[6656 + idx]);
        float fg = ff * ov + (cfg - ov);
        float ig = ii * ov + (cin - ov);
        float cy = fg * cb[idx] + ig * gg;
        cb[idx] = cy;
        float hy = oo * tanhf(cy);
        hb[idx] = hy;
        ob[idx] = hy;
    }
}

// ===================== launch =====================

extern "C" void kernel_launch(void* const* d_in, const int* in_sizes, int n_in,
                              void* d_out, int out_size, void* d_ws, size_t ws_size,
                              hipStream_t stream) {
    const float* enc    = (const float*)d_in[0];
    const float* W_att1 = (const float*)d_in[2];
    const float* b_att1 = (const float*)d_in[3];
    const float* w_att2 = (const float*)d_in[4];
    const float* W_ih   = (const float*)d_in[5];
    const float* b_ih   = (const float*)d_in[6];
    const float* W_hh   = (const float*)d_in[7];
    const float* b_hh   = (const float*)d_in[8];
    float* out = (float*)d_out;
    float* ws  = (float*)d_ws;

    if (ws_size >= 152600576ull) {
        // ---------------- MFMA split-bf16 path ----------------
        float* P    = ws;                  // 8388608 f
        float* hWp  = P + 8388608;         // 524288 f
        float* ebuf = hWp + 524288;        // 8192 f
        float* gp   = ebuf + 8192;         // 2*64*8704 = 1114112 f
        float* c    = gp + 1114112;        // 131072 f
        u16* xh  = (u16*)(c + 131072);     // 64*3072
        u16* xl  = xh + 196608;            // 64*3072
        u16* Wth = xl + 196608;            // 8704*3072
        u16* Wtl = Wth + 26738688;         // 8704*3072
        u16* Wta = Wtl + 26738688;         // 1024*2048

        k_init2<<<768, 256, 0, stream>>>(c, xh, xl);
        k_cvt<true><<<dim3(136, 48), 256, 0, stream>>>(W_ih, W_hh, 1024, GG, KTOT, Wth, Wtl);
        const float* Wh_att = W_att1 + 1024 * 1024;
        k_cvt<false><<<dim3(16, 32), 256, 0, stream>>>(Wh_att, Wh_att, 2048, DHH, 2048, Wta, Wta);
        k_P<<<dim3(16, 128), 256, 0, stream>>>(enc, W_att1, b_att1, P);

        for (int t = 0; t < TDEC; ++t) {
            k_mma1<<<dim3(16, 8), 256, 0, stream>>>(xh, Wta, hWp);
            k_e<<<dim3(BB, 4), 256, 0, stream>>>(P, hWp, w_att2, ebuf);
            k_sc2<<<dim3(BB, 4), 256, 0, stream>>>(ebuf, enc, xh, xl);
            k_mma3<<<dim3(136, 2), 256, 0, stream>>>(xh, xl, Wth, Wtl, gp);
            k_pw2<<<BB, 256, 0, stream>>>(gp, b_ih, b_hh, xh, xl, c, out, t);
        }
    } else if (ws_size >= 12591104ull * 4ull) {
        // ---------------- f32 fallback (round-1) path ----------------
        float* P    = ws;
        float* hWp  = P + 8388608;
        float* ebuf = hWp + 524288;
        float* ctx  = ebuf + 8192;
        float* gp   = ctx + 65536;
        float* h    = gp + 3342336;
        float* c    = h + 131072;

        k_init<<<512, 256, 0, stream>>>(h, c);
        k_P<<<dim3(16, 128), 256, 0, stream>>>(enc, W_att1, b_att1, P);

        const float* Wh_att = W_att1 + 1024 * 1024;
        for (int t = 0; t < TDEC; ++t) {
            k_skinny<256><<<dim3(16, 8), 256, 0, stream>>>(h, h, Wh_att, Wh_att,
                                                           2048, 2048, DHH, hWp);
            k_e<<<dim3(BB, 4), 256, 0, stream>>>(P, hWp, w_att2, ebuf);
            k_sc_f32<<<dim3(BB, 4), 256, 0, stream>>>(ebuf, enc, ctx);
            k_skinny<512><<<dim3(136, 6), 256, 0, stream>>>(ctx, h, W_ih, W_hh,
                                                            1024, 2048, GG, gp);
            k_pw_f32<<<BB, 256, 0, stream>>>(gp, b_ih, b_hh, h, c, out, t);
        }
    }
}

// Round 3
// 10138.387 us; speedup vs baseline: 1.1931x; 1.1931x over previous
//
#include <hip/hip_runtime.h>
#include <math.h>

#define BB   64
#define TENC 128
#define TDEC 64
#define DHH  1024
#define DVV  2048
#define NCHN 256
#define GG   8704   // 4*DV + 2*NCH
#define KTOT 3072   // DH + DV

typedef unsigned short u16;
typedef __bf16 bf16x8 __attribute__((ext_vector_type(8)));
typedef float  f32x4  __attribute__((ext_vector_type(4)));

__device__ __forceinline__ u16 f2bf(float f) {
    unsigned u = __float_as_uint(f);
    unsigned r = (u + 0x7fffu + ((u >> 16) & 1u)) >> 16;
    return (u16)r;
}
__device__ __forceinline__ float bf2f(u16 s) { return __uint_as_float(((unsigned)s) << 16); }
__device__ __forceinline__ float tanh_fast(float x) {
    float xc = fminf(fmaxf(x, -15.f), 15.f);
    float t = __expf(2.f * xc);
    return 1.f - 2.f * __builtin_amdgcn_rcpf(t + 1.f);
}
__device__ __forceinline__ float sigmoid_fast(float x) {
    float xc = fminf(fmaxf(x, -30.f), 30.f);
    return __builtin_amdgcn_rcpf(1.f + __expf(-xc));
}

// ===================== precompute kernels =====================

// zero recurrent state + bf16 x buffers (runs AFTER precompute; xh/xl alias pre region)
__global__ __launch_bounds__(256) void k_init2(float* __restrict__ c,
                                               u16* __restrict__ xh,
                                               u16* __restrict__ xl) {
    int i = blockIdx.x * 256 + threadIdx.x;   // grid 768 -> 196608
    xh[i] = 0; xl[i] = 0;
    if (i < BB * DVV) c[i] = 0.f;
}

// transpose+convert: D[n][k] = bf16(S[k][n]) (hi, optionally lo residual)
template <bool LO>
__global__ __launch_bounds__(256) void k_cvt(const float* __restrict__ S1,
                                             const float* __restrict__ S2,
                                             int K1, int N, int K,
                                             u16* __restrict__ Dh,
                                             u16* __restrict__ Dl) {
    __shared__ float t[64][65];
    int n0 = blockIdx.x * 64, k0 = blockIdx.y * 64;
    int tid = threadIdx.x;
    int cn = tid & 63, r4 = tid >> 6;
#pragma unroll
    for (int p = 0; p < 16; ++p) {
        int kk = p * 4 + r4;
        int kg = k0 + kk;
        const float* src = (kg < K1) ? S1 + (size_t)kg * N : S2 + (size_t)(kg - K1) * N;
        t[kk][cn] = src[n0 + cn];
    }
    __syncthreads();
    int ck = tid & 63, n4 = tid >> 6;
#pragma unroll
    for (int p = 0; p < 16; ++p) {
        int nn = p * 4 + n4;
        float w = t[ck][nn];
        u16 hi = f2bf(w);
        size_t o = (size_t)(n0 + nn) * K + k0 + ck;
        Dh[o] = hi;
        if (LO) Dl[o] = f2bf(w - bf2f(hi));
    }
}

// elementwise hi/lo convert (row-major, no transpose)
__global__ __launch_bounds__(256) void k_cvt_rm(const float* __restrict__ src,
                                                u16* __restrict__ dh,
                                                u16* __restrict__ dl, int n) {
    for (int i = blockIdx.x * 256 + threadIdx.x; i < n; i += gridDim.x * 256) {
        float w = src[i];
        u16 hi = f2bf(w);
        dh[i] = hi;
        dl[i] = f2bf(w - bf2f(hi));
    }
}

// P = enc @ W1[:DH] + b1 via 3-term hi/lo bf16 MFMA. grid (16 n-tiles, 128 m-tiles)
__global__ __launch_bounds__(256) void k_mmaP(const u16* __restrict__ ench,
                                              const u16* __restrict__ encl,
                                              const u16* __restrict__ W1h,
                                              const u16* __restrict__ W1l,
                                              const float* __restrict__ b1,
                                              float* __restrict__ P) {
    int n0 = blockIdx.x * 64, m0 = blockIdx.y * 64;
    int wv = threadIdx.x >> 6, l = threadIdx.x & 63;
    int lr = l & 15, lk = (l >> 4) * 8;
    int n = n0 + wv * 16 + lr;
    const u16* wph = W1h + (size_t)n * DHH + lk;
    const u16* wpl = W1l + (size_t)n * DHH + lk;
    const u16* aph = ench + (size_t)(m0 + lr) * DHH + lk;
    const u16* apl = encl + (size_t)(m0 + lr) * DHH + lk;
    f32x4 z = {0.f, 0.f, 0.f, 0.f};
    f32x4 acc[4] = {z, z, z, z};
    for (int k = 0; k < DHH; k += 32) {
        bf16x8 bh = *(const bf16x8*)(wph + k);
        bf16x8 bl = *(const bf16x8*)(wpl + k);
#pragma unroll
        for (int mf = 0; mf < 4; ++mf) {
            size_t ao = (size_t)mf * 16 * DHH + k;
            bf16x8 ah = *(const bf16x8*)(aph + ao);
            bf16x8 al = *(const bf16x8*)(apl + ao);
            acc[mf] = __builtin_amdgcn_mfma_f32_16x16x32_bf16(ah, bh, acc[mf], 0, 0, 0);
            acc[mf] = __builtin_amdgcn_mfma_f32_16x16x32_bf16(ah, bl, acc[mf], 0, 0, 0);
            acc[mf] = __builtin_amdgcn_mfma_f32_16x16x32_bf16(al, bh, acc[mf], 0, 0, 0);
        }
    }
    float bias = b1[n];
#pragma unroll
    for (int mf = 0; mf < 4; ++mf)
#pragma unroll
        for (int r = 0; r < 4; ++r) {
            int m = m0 + mf * 16 + (l >> 4) * 4 + r;
            P[(size_t)m * DHH + n] = acc[mf][r] + bias;
        }
}

// f32 fallback P (tier 2)
__global__ __launch_bounds__(256) void k_P(const float* __restrict__ enc,
                                           const float* __restrict__ W1,
                                           const float* __restrict__ b1,
                                           float* __restrict__ P) {
    __shared__ float As[32][68];
    __shared__ float Bs[32][68];
    int j0 = blockIdx.x * 64;
    int m0 = blockIdx.y * 64;
    int tid = threadIdx.x;
    int jg = tid & 15, bg = tid >> 4;
    float acc[4][4] = {};
    for (int k0 = 0; k0 < DHH; k0 += 32) {
#pragma unroll
        for (int p = 0; p < 8; ++p) {
            int r = p * 8 + (tid >> 5);
            int kk = tid & 31;
            As[kk][r] = enc[(size_t)(m0 + r) * DHH + k0 + kk];
        }
#pragma unroll
        for (int p = 0; p < 8; ++p) {
            int kk = p * 4 + (tid >> 6);
            int jl = tid & 63;
            Bs[kk][jl] = W1[(size_t)(k0 + kk) * DHH + j0 + jl];
        }
        __syncthreads();
#pragma unroll
        for (int kk = 0; kk < 32; ++kk) {
            float4 a = *(const float4*)&As[kk][bg * 4];
            float4 b = *(const float4*)&Bs[kk][jg * 4];
            float av[4] = {a.x, a.y, a.z, a.w};
            float bv[4] = {b.x, b.y, b.z, b.w};
#pragma unroll
            for (int i = 0; i < 4; ++i)
#pragma unroll
                for (int j = 0; j < 4; ++j) acc[i][j] += av[i] * bv[j];
        }
        __syncthreads();
    }
    float4 bb = *(const float4*)&b1[j0 + jg * 4];
    float bia[4] = {bb.x, bb.y, bb.z, bb.w};
#pragma unroll
    for (int i = 0; i < 4; ++i) {
        int r = m0 + bg * 4 + i;
        float4 v = make_float4(acc[i][0] + bia[0], acc[i][1] + bia[1],
                               acc[i][2] + bia[2], acc[i][3] + bia[3]);
        *(float4*)&P[(size_t)r * DHH + j0 + jg * 4] = v;
    }
}

// ===================== per-step kernels =====================

// hW = x_h @ Wta^T : M=64,N=1024,K=2048. 512 thr: 8 waves = 4 n-tiles x 2 k-halves.
// grid (16, 8): effective k-split 16, stored as 8 segments.
__global__ __launch_bounds__(512) void k_mma1(const u16* __restrict__ xh,
                                              const u16* __restrict__ Wta,
                                              float* __restrict__ hWp) {
    __shared__ float red[64 * 68];
    int n0 = blockIdx.x * 64;
    int kseg = blockIdx.y;                 // 8 segs of 256
    int tid = threadIdx.x;
    int wv = tid >> 6, l = tid & 63;
    int wn = wv & 3, kh = wv >> 2;
    int lr = l & 15, lk = (l >> 4) * 8;
    int n = n0 + wn * 16 + lr;
    const u16* wp = Wta + (size_t)n * 2048 + lk;
    const u16* ap = xh + (size_t)lr * KTOT + 1024 + lk;   // h part of x
    f32x4 z = {0.f, 0.f, 0.f, 0.f};
    f32x4 acc[4] = {z, z, z, z};
    int kbeg = kseg * 256 + kh * 128;
    for (int k = kbeg; k < kbeg + 128; k += 32) {
        bf16x8 bfrag = *(const bf16x8*)(wp + k);
#pragma unroll
        for (int mf = 0; mf < 4; ++mf) {
            bf16x8 a = *(const bf16x8*)(ap + (size_t)mf * 16 * KTOT + k);
            acc[mf] = __builtin_amdgcn_mfma_f32_16x16x32_bf16(a, bfrag, acc[mf], 0, 0, 0);
        }
    }
    int moff = (l >> 4) * 4;
    if (kh == 0) {
#pragma unroll
        for (int mf = 0; mf < 4; ++mf)
#pragma unroll
            for (int r = 0; r < 4; ++r)
                red[(mf * 16 + moff + r) * 68 + wn * 16 + lr] = acc[mf][r];
    }
    __syncthreads();
    if (kh == 1) {
        float* dst = hWp + (size_t)kseg * 64 * DHH;
#pragma unroll
        for (int mf = 0; mf < 4; ++mf)
#pragma unroll
            for (int r = 0; r < 4; ++r) {
                int m = mf * 16 + moff + r;
                dst[(size_t)m * DHH + n] = acc[mf][r] + red[m * 68 + wn * 16 + lr];
            }
    }
}

// gates partials: 3-term hi/lo. 512 thr, 8 waves = 4 n-tiles x 2 k-halves. grid (136, SEG)
template <int SEG>
__global__ __launch_bounds__(512) void k_mma3(const u16* __restrict__ xh,
                                              const u16* __restrict__ xl,
                                              const u16* __restrict__ Wh,
                                              const u16* __restrict__ Wl,
                                              float* __restrict__ part) {
    __shared__ float red[64 * 68];
    int n0 = blockIdx.x * 64;
    int kseg = blockIdx.y;
    int tid = threadIdx.x;
    int wv = tid >> 6, l = tid & 63;
    int wn = wv & 3, kh = wv >> 2;
    int lr = l & 15, lk = (l >> 4) * 8;
    int n = n0 + wn * 16 + lr;
    const u16* wph = Wh + (size_t)n * KTOT + lk;
    const u16* wpl = Wl + (size_t)n * KTOT + lk;
    const u16* aph = xh + (size_t)lr * KTOT + lk;
    const u16* apl = xl + (size_t)lr * KTOT + lk;
    f32x4 z = {0.f, 0.f, 0.f, 0.f};
    f32x4 acc[4] = {z, z, z, z};
    const int KSEG = KTOT / SEG;
    const int KH = KSEG / 2;
    int kbeg = kseg * KSEG + kh * KH;
    for (int k = kbeg; k < kbeg + KH; k += 32) {
        bf16x8 bh = *(const bf16x8*)(wph + k);
        bf16x8 bl = *(const bf16x8*)(wpl + k);
#pragma unroll
        for (int mf = 0; mf < 4; ++mf) {
            size_t ao = (size_t)mf * 16 * KTOT + k;
            bf16x8 ah = *(const bf16x8*)(aph + ao);
            bf16x8 al = *(const bf16x8*)(apl + ao);
            acc[mf] = __builtin_amdgcn_mfma_f32_16x16x32_bf16(ah, bh, acc[mf], 0, 0, 0);
            acc[mf] = __builtin_amdgcn_mfma_f32_16x16x32_bf16(ah, bl, acc[mf], 0, 0, 0);
            acc[mf] = __builtin_amdgcn_mfma_f32_16x16x32_bf16(al, bh, acc[mf], 0, 0, 0);
        }
    }
    int moff = (l >> 4) * 4;
    if (kh == 0) {
#pragma unroll
        for (int mf = 0; mf < 4; ++mf)
#pragma unroll
            for (int r = 0; r < 4; ++r)
                red[(mf * 16 + moff + r) * 68 + wn * 16 + lr] = acc[mf][r];
    }
    __syncthreads();
    if (kh == 1) {
        float* dst = part + (size_t)kseg * 64 * GG;
#pragma unroll
        for (int mf = 0; mf < 4; ++mf)
#pragma unroll
            for (int r = 0; r < 4; ++r) {
                int m = mf * 16 + moff + r;
                dst[(size_t)m * GG + n] = acc[mf][r] + red[m * 68 + wn * 16 + lr];
            }
    }
}

// e[b,t] = sum_d tanh(P[b,t,d] + hW[b,d]) * w2[d]  (reduces 8 hW partials). grid (64,4)
__global__ __launch_bounds__(256) void k_e(const float* __restrict__ P,
                                           const float* __restrict__ hWp,
                                           const float* __restrict__ w2,
                                           float* __restrict__ e) {
    int b = blockIdx.x, tg = blockIdx.y;
    __shared__ float hw[DHH];
    __shared__ float w2s[DHH];
    int tid = threadIdx.x;
    {
        float4 s = {0.f, 0.f, 0.f, 0.f};
#pragma unroll
        for (int ks = 0; ks < 8; ++ks) {
            float4 v = *(const float4*)&hWp[(size_t)(ks * 64 + b) * DHH + tid * 4];
            s.x += v.x; s.y += v.y; s.z += v.z; s.w += v.w;
        }
        *(float4*)&hw[tid * 4] = s;
        *(float4*)&w2s[tid * 4] = *(const float4*)&w2[tid * 4];
    }
    __syncthreads();
    int wave = tid >> 6, lane = tid & 63;
    const float* Pb = P + (size_t)b * TENC * DHH;
    for (int tt = 0; tt < 8; ++tt) {
        int t = tg * 32 + wave * 8 + tt;
        const float* Pr = Pb + (size_t)t * DHH;
        float s = 0.f;
#pragma unroll
        for (int i = 0; i < 16; ++i) {
            int d = i * 64 + lane;
            s += tanh_fast(Pr[d] + hw[d]) * w2s[d];
        }
#pragma unroll
        for (int off = 32; off > 0; off >>= 1) s += __shfl_down(s, off);
        if (lane == 0) e[b * TENC + t] = s;
    }
}

// softmax over t + context -> bf16 hi/lo into x cols 0..1023. grid (64,4): (b, d-quarter)
__global__ __launch_bounds__(256) void k_sc2(const float* __restrict__ e,
                                             const float* __restrict__ enc,
                                             u16* __restrict__ xh,
                                             u16* __restrict__ xl) {
    int b = blockIdx.x, dq = blockIdx.y;
    __shared__ float al[TENC];
    __shared__ float red[256];
    __shared__ float4 pr[4][64];
    int tid = threadIdx.x;
    float v = (tid < TENC) ? e[b * TENC + tid] : -3.0e38f;
    red[tid] = v;
    __syncthreads();
    for (int s = 128; s > 0; s >>= 1) {
        if (tid < s) red[tid] = fmaxf(red[tid], red[tid + s]);
        __syncthreads();
    }
    float mx = red[0];
    __syncthreads();
    float ex = (tid < TENC) ? __expf(v - mx) : 0.f;
    red[tid] = ex;
    __syncthreads();
    for (int s = 128; s > 0; s >>= 1) {
        if (tid < s) red[tid] += red[tid + s];
        __syncthreads();
    }
    float inv = 1.f / red[0];
    if (tid < TENC) al[tid] = ex * inv;
    __syncthreads();
    int w = tid >> 6, l = tid & 63;
    int dbase = dq * 256 + l * 4;
    const float* ep = enc + ((size_t)b * TENC + w * 32) * DHH + dbase;
    float4 acc = {0.f, 0.f, 0.f, 0.f};
#pragma unroll 8
    for (int tt = 0; tt < 32; ++tt) {
        float a = al[w * 32 + tt];
        float4 vv = *(const float4*)(ep + (size_t)tt * DHH);
        acc.x += a * vv.x; acc.y += a * vv.y; acc.z += a * vv.z; acc.w += a * vv.w;
    }
    pr[w][l] = acc;
    __syncthreads();
    if (tid < 64) {
        float4 a0 = pr[0][tid], a1 = pr[1][tid], a2 = pr[2][tid], a3 = pr[3][tid];
        float r0 = a0.x + a1.x + a2.x + a3.x;
        float r1 = a0.y + a1.y + a2.y + a3.y;
        float r2 = a0.z + a1.z + a2.z + a3.z;
        float r3 = a0.w + a1.w + a2.w + a3.w;
        size_t o = (size_t)b * KTOT + dq * 256 + tid * 4;
        u16 h0 = f2bf(r0), h1 = f2bf(r1), h2 = f2bf(r2), h3 = f2bf(r3);
        ushort4 hv = {h0, h1, h2, h3};
        ushort4 lv = {f2bf(r0 - bf2f(h0)), f2bf(r1 - bf2f(h1)),
                      f2bf(r2 - bf2f(h2)), f2bf(r3 - bf2f(h3))};
        *(ushort4*)&xh[o] = hv;
        *(ushort4*)&xl[o] = lv;
    }
}

// reduce gate partials + biases, cumsoftmax, ON-LSTM update; h -> bf16 hi/lo + out
__global__ __launch_bounds__(256) void k_pw2(const float* __restrict__ part, int nseg,
                                             const float* __restrict__ bih,
                                             const float* __restrict__ bhh,
                                             u16* __restrict__ xh,
                                             u16* __restrict__ xl,
                                             float* __restrict__ c,
                                             float* __restrict__ out, int t) {
    int b = blockIdx.x;
    __shared__ float g[GG];
    __shared__ float cs1[NCHN], cs2[NCHN], t1[NCHN], t2[NCHN];
    int tid = threadIdx.x;
    for (int p = 0; p < 34; ++p) {
        int j = p * 256 + tid;
        float s = bih[j] + bhh[j];
        for (int ks = 0; ks < nseg; ++ks) s += part[(size_t)(ks * 64 + b) * GG + j];
        g[j] = s;
    }
    __syncthreads();
    float x1 = g[tid], x2 = g[NCHN + tid];
    t1[tid] = x1; t2[tid] = x2;
    __syncthreads();
    for (int s = 128; s > 0; s >>= 1) {
        if (tid < s) { t1[tid] = fmaxf(t1[tid], t1[tid + s]); t2[tid] = fmaxf(t2[tid], t2[tid + s]); }
        __syncthreads();
    }
    float m1 = t1[0], m2 = t2[0];
    __syncthreads();
    float e1 = __expf(x1 - m1), e2 = __expf(x2 - m2);
    t1[tid] = e1; t2[tid] = e2;
    __syncthreads();
    for (int s = 128; s > 0; s >>= 1) {
        if (tid < s) { t1[tid] += t1[tid + s]; t2[tid] += t2[tid + s]; }
        __syncthreads();
    }
    float inv1 = 1.f / t1[0], inv2 = 1.f / t2[0];
    __syncthreads();
    cs1[tid] = e1; cs2[tid] = e2;
    __syncthreads();
    for (int off = 1; off < NCHN; off <<= 1) {
        float a1 = (tid >= off) ? cs1[tid - off] : 0.f;
        float a2 = (tid >= off) ? cs2[tid - off] : 0.f;
        __syncthreads();
        cs1[tid] += a1; cs2[tid] += a2;
        __syncthreads();
    }
    float* cb = c + (size_t)b * DVV;
    float* ob = out + ((size_t)b * TDEC + t) * DVV;
    u16* xhb = xh + (size_t)b * KTOT + 1024;
    u16* xlb = xl + (size_t)b * KTOT + 1024;
    for (int p = 0; p < 8; ++p) {
        int idx = p * 256 + tid;
        int ch = idx >> 3;
        float cin = 1.f - cs1[ch] * inv1;
        float cfg = cs2[ch] * inv2;
        float ov = cfg * cin;
        float oo = sigmoid_fast(g[512 + idx]);
        float gg = tanh_fast(g[2560 + idx]);
        float ii = sigmoid_fast(g[4608 + idx]);
        float ff = sigmoid_fast(g[6656 + idx]);
        float fg = ff * ov + (cfg - ov);
        float ig = ii * ov + (cin - ov);
        float cy = fg * cb[idx] + ig * gg;
        cb[idx] = cy;
        float hy = oo * tanh_fast(cy);
        ob[idx] = hy;
        u16 hh = f2bf(hy);
        xhb[idx] = hh;
        xlb[idx] = f2bf(hy - bf2f(hh));
    }
}

// ===================== launch =====================

extern "C" void kernel_launch(void* const* d_in, const int* in_sizes, int n_in,
                              void* d_out, int out_size, void* d_ws, size_t ws_size,
                              hipStream_t stream) {
    const float* enc    = (const float*)d_in[0];
    const float* W_att1 = (const float*)d_in[2];
    const float* b_att1 = (const float*)d_in[3];
    const float* w_att2 = (const float*)d_in[4];
    const float* W_ih   = (const float*)d_in[5];
    const float* b_ih   = (const float*)d_in[6];
    const float* W_hh   = (const float*)d_in[7];
    const float* b_hh   = (const float*)d_in[8];
    float* out = (float*)d_out;
    float* ws  = (float*)d_ws;
    const float* Wh_att = W_att1 + 1024 * 1024;

    if (ws_size >= 182976512ull) {
        // ---------------- tier 1: full MFMA, SEG=4, MFMA P ----------------
        float* P   = ws;                          // 8388608 f
        float* c   = P + 8388608;                 // 131072 f
        u16* Wth   = (u16*)(c + 131072);          // 26738688
        u16* Wtl   = Wth + 26738688;              // 26738688
        u16* Wta   = Wtl + 26738688;              // 2097152
        u16* region = Wta + 2097152;
        // pre-region (aliased with decode buffers):
        u16* ench = region;                       // 8388608
        u16* encl = ench + 8388608;               // 8388608
        u16* W1h  = encl + 8388608;               // 1048576
        u16* W1l  = W1h + 1048576;                // 1048576
        // decode region (aliases pre):
        float* gp   = (float*)region;             // 4*64*8704 = 2228224 f
        float* hWp  = gp + 2228224;               // 8*64*1024 = 524288 f
        float* ebuf = hWp + 524288;               // 8192 f
        u16* xh     = (u16*)(ebuf + 8192);        // 196608
        u16* xl     = xh + 196608;                // 196608

        k_cvt<true><<<dim3(136, 48), 256, 0, stream>>>(W_ih, W_hh, 1024, GG, KTOT, Wth, Wtl);
        k_cvt<false><<<dim3(16, 32), 256, 0, stream>>>(Wh_att, Wh_att, 2048, DHH, 2048, Wta, Wta);
        k_cvt<true><<<dim3(16, 16), 256, 0, stream>>>(W_att1, W_att1, 2048, DHH, DHH, W1h, W1l);
        k_cvt_rm<<<4096, 256, 0, stream>>>(enc, ench, encl, 8388608);
        k_mmaP<<<dim3(16, 128), 256, 0, stream>>>(ench, encl, W1h, W1l, b_att1, P);
        k_init2<<<768, 256, 0, stream>>>(c, xh, xl);

        for (int t = 0; t < TDEC; ++t) {
            k_mma1<<<dim3(16, 8), 512, 0, stream>>>(xh, Wta, hWp);
            k_e<<<dim3(BB, 4), 256, 0, stream>>>(P, hWp, w_att2, ebuf);
            k_sc2<<<dim3(BB, 4), 256, 0, stream>>>(ebuf, enc, xh, xl);
            k_mma3<4><<<dim3(136, 4), 512, 0, stream>>>(xh, xl, Wth, Wtl, gp);
            k_pw2<<<BB, 256, 0, stream>>>(gp, 4, b_ih, b_hh, xh, xl, c, out, t);
        }
    } else if (ws_size >= 152600576ull) {
        // ---------------- tier 2: proven 152.6MB budget, SEG=2, f32 P ----------------
        float* P    = ws;                  // 8388608 f
        float* hWp  = P + 8388608;         // 524288 f
        float* ebuf = hWp + 524288;        // 8192 f
        float* gp   = ebuf + 8192;         // 2*64*8704 = 1114112 f
        float* c    = gp + 1114112;        // 131072 f
        u16* xh  = (u16*)(c + 131072);     // 196608
        u16* xl  = xh + 196608;            // 196608
        u16* Wth = xl + 196608;            // 26738688
        u16* Wtl = Wth + 26738688;         // 26738688
        u16* Wta = Wtl + 26738688;         // 2097152

        k_cvt<true><<<dim3(136, 48), 256, 0, stream>>>(W_ih, W_hh, 1024, GG, KTOT, Wth, Wtl);
        k_cvt<false><<<dim3(16, 32), 256, 0, stream>>>(Wh_att, Wh_att, 2048, DHH, 2048, Wta, Wta);
        k_P<<<dim3(16, 128), 256, 0, stream>>>(enc, W_att1, b_att1, P);
        k_init2<<<768, 256, 0, stream>>>(c, xh, xl);

        for (int t = 0; t < TDEC; ++t) {
            k_mma1<<<dim3(16, 8), 512, 0, stream>>>(xh, Wta, hWp);
            k_e<<<dim3(BB, 4), 256, 0, stream>>>(P, hWp, w_att2, ebuf);
            k_sc2<<<dim3(BB, 4), 256, 0, stream>>>(ebuf, enc, xh, xl);
            k_mma3<2><<<dim3(136, 2), 512, 0, stream>>>(xh, xl, Wth, Wtl, gp);
            k_pw2<<<BB, 256, 0, stream>>>(gp, 2, b_ih, b_hh, xh, xl, c, out, t);
        }
    }
}